// Round 15
// baseline (699.291 us; speedup 1.0000x reference)
//
#include <hip/hip_runtime.h>
#include <hip/hip_bf16.h>
#include <stdint.h>

#define Bv 128
#define Tv 512
#define Iv 64
#define Hv 512
#define Ov 64

typedef __attribute__((ext_vector_type(8))) short bv8;    // 8 bf16 for MFMA A/B
typedef __attribute__((ext_vector_type(4))) float fv4;    // MFMA C/D
typedef __attribute__((ext_vector_type(4))) unsigned uv4;
typedef __attribute__((ext_vector_type(2))) unsigned uv2;

#define LOG2E 1.44269504f
#define TWOLOG2E 2.88539008f

static __device__ __forceinline__ unsigned short f2bf(float f) {
  unsigned u = __builtin_bit_cast(unsigned, f);
  u += 0x7fffu + ((u >> 16) & 1u);           // RNE
  return (unsigned short)(u >> 16);
}
static __device__ __forceinline__ float bf2f(unsigned short s) {
  return __builtin_bit_cast(float, ((unsigned)s) << 16);
}

// Full 64-lane sum, result replicated in every lane. Fused single-instruction
// DPP adds for the 4 in-row levels.
static __device__ __forceinline__ float wave_red(float v) {
  float d;
  asm("v_add_f32_dpp %0, %1, %1 quad_perm:[1,0,3,2] row_mask:0xf bank_mask:0xf"
      : "=v"(d) : "v"(v)); v = d;
  asm("v_add_f32_dpp %0, %1, %1 quad_perm:[2,3,0,1] row_mask:0xf bank_mask:0xf"
      : "=v"(d) : "v"(v)); v = d;
  asm("v_add_f32_dpp %0, %1, %1 row_ror:4 row_mask:0xf bank_mask:0xf"
      : "=v"(d) : "v"(v)); v = d;
  asm("v_add_f32_dpp %0, %1, %1 row_ror:8 row_mask:0xf bank_mask:0xf"
      : "=v"(d) : "v"(v)); v = d;
  unsigned a = __builtin_bit_cast(unsigned, v);
  uv2 p = __builtin_amdgcn_permlane16_swap(a, a, false, false);
  v = __builtin_bit_cast(float, p[0]) + __builtin_bit_cast(float, p[1]);  // + v[lane^16]
  a = __builtin_bit_cast(unsigned, v);
  uv2 q = __builtin_amdgcn_permlane32_swap(a, a, false, false);
  v = __builtin_bit_cast(float, q[0]) + __builtin_bit_cast(float, q[1]);  // + v[lane^32]
  return v;
}

// ---------------------------------------------------------------------------
// K1: input projections. Stores NEGATED, log2e-scaled values:
//   irz slot = pack( -L*(iz), -L*(ir) ) bf16x2; ih = -2L*(ih) bf16.
// ---------------------------------------------------------------------------
__global__ __launch_bounds__(256) void proj_kernel(
    const float* __restrict__ u,
    const float* __restrict__ Wir, const float* __restrict__ bir,
    const float* __restrict__ Wiz, const float* __restrict__ biz,
    const float* __restrict__ Wih, const float* __restrict__ bih,
    unsigned* __restrict__ irz, unsigned short* __restrict__ ihb)
{
  __shared__ __align__(16) unsigned short As[64][72];  // bf16, padded stride
  const int bt0 = blockIdx.x * 64;
  const int h0b = blockIdx.y * 64;
  const int tid = threadIdx.x;
  {  // stage u tile f32 -> bf16 LDS
    const int r = tid >> 2, ksg = (tid & 3) * 16;
    const float* src = u + (size_t)(bt0 + r) * Iv + ksg;
    unsigned short tmp[16];
#pragma unroll
    for (int i = 0; i < 16; i += 4) {
      float4 v = *(const float4*)(src + i);
      tmp[i] = f2bf(v.x); tmp[i+1] = f2bf(v.y); tmp[i+2] = f2bf(v.z); tmp[i+3] = f2bf(v.w);
    }
    *(uv4*)&As[r][ksg]     = *(uv4*)&tmp[0];
    *(uv4*)&As[r][ksg + 8] = *(uv4*)&tmp[8];
  }
  __syncthreads();
  const int wave = tid >> 6, lane = tid & 63;
  const int n = lane & 15, q = lane >> 4;
  const int h = h0b + wave * 16 + n;
  const float* Wg[3] = {Wir, Wiz, Wih};
  const float SCL[3] = {-LOG2E, -LOG2E, -TWOLOG2E};
  bv8 bfrag[3][2];
#pragma unroll
  for (int g = 0; g < 3; ++g)
#pragma unroll
    for (int ks = 0; ks < 2; ++ks) {
      const float* wp = Wg[g] + (size_t)h * Iv + ks * 32 + q * 8;
      float4 w0 = *(const float4*)wp, w1 = *(const float4*)(wp + 4);
      const float s = SCL[g];
      bv8 f;
      f[0] = (short)f2bf(w0.x * s); f[1] = (short)f2bf(w0.y * s);
      f[2] = (short)f2bf(w0.z * s); f[3] = (short)f2bf(w0.w * s);
      f[4] = (short)f2bf(w1.x * s); f[5] = (short)f2bf(w1.y * s);
      f[6] = (short)f2bf(w1.z * s); f[7] = (short)f2bf(w1.w * s);
      bfrag[g][ks] = f;
    }
  const float bs0 = bir[h] * -LOG2E, bs1 = biz[h] * -LOG2E, bs2 = bih[h] * -TWOLOG2E;
#pragma unroll
  for (int sub = 0; sub < 4; ++sub) {
    bv8 a0 = *(const bv8*)&As[sub * 16 + n][q * 8];
    bv8 a1 = *(const bv8*)&As[sub * 16 + n][32 + q * 8];
    fv4 ar = {0.f,0.f,0.f,0.f}, az = {0.f,0.f,0.f,0.f}, ah = {0.f,0.f,0.f,0.f};
    ar = __builtin_amdgcn_mfma_f32_16x16x32_bf16(a0, bfrag[0][0], ar, 0, 0, 0);
    ar = __builtin_amdgcn_mfma_f32_16x16x32_bf16(a1, bfrag[0][1], ar, 0, 0, 0);
    az = __builtin_amdgcn_mfma_f32_16x16x32_bf16(a0, bfrag[1][0], az, 0, 0, 0);
    az = __builtin_amdgcn_mfma_f32_16x16x32_bf16(a1, bfrag[1][1], az, 0, 0, 0);
    ah = __builtin_amdgcn_mfma_f32_16x16x32_bf16(a0, bfrag[2][0], ah, 0, 0, 0);
    ah = __builtin_amdgcn_mfma_f32_16x16x32_bf16(a1, bfrag[2][1], ah, 0, 0, 0);
#pragma unroll
    for (int j = 0; j < 4; ++j) {
      const int row = bt0 + sub * 16 + q * 4 + j;   // C/D: col=lane&15, row=(lane>>4)*4+j
      const size_t slot = (size_t)row * Hv + h;
      irz[slot] = ((unsigned)f2bf(az[j] + bs1) << 16) | (unsigned)f2bf(ar[j] + bs0);
      ihb[slot] = f2bf(ah[j] + bs2);
    }
  }
}

// ---------------------------------------------------------------------------
// K2: the scan. 128 blocks x 128 threads = 2 waves per batch; wave w owns
// h in [w*256, w*256+256), lane owns 4 h. R14 geometry, two fixes:
//  (a) RAW s_barrier (+ manual lgkmcnt(0)) for the 2 cross-wave exchanges —
//      __syncthreads would drain vmcnt(0) each step, killing the prefetch.
//  (b) asm-volatile global loads (cannot be sunk by the allocator), with
//      counted s_waitcnt vmcnt(4) (first step: 3) + sched_barrier before use.
//      Queue/step: 3 loads + 1 store; the wait retires exactly this step's
//      loads, never the store or next step's loads.
// ---------------------------------------------------------------------------
#define SECF 2560                    // floats per matrix section (128 thr x 20)
#define XB1 (6 * SECF)               // X1[2][8]
#define XB2 (6 * SECF + 16)          // X2[2][4]

struct Buf { uv4 irz; uv2 ih2; fv4 nz; };

__global__ __launch_bounds__(128, 1) void scan_kernel(
    const float* __restrict__ x0, const float* __restrict__ noise,
    const float* __restrict__ Nhr, const float* __restrict__ Mhr,
    const float* __restrict__ Nhz, const float* __restrict__ Mhz,
    const float* __restrict__ Nhh, const float* __restrict__ Mhh,
    unsigned* __restrict__ traj, const unsigned short* __restrict__ ihb,
    float* __restrict__ xlast)
{
  __shared__ __align__(16) float S[6 * SECF + 32];   // 60KB matrices + exchange
  const int tid = threadIdx.x;
  const int w = tid >> 6, lane = tid & 63;
  const int b = blockIdx.x;
  const int h0 = w * 256 + lane * 4;                 // this thread's 4 h rows
  const int fb = tid * 20;                           // per-thread slot base (floats)

#define LDQ(sec, s) (*(const fv4*)&S[(sec) * SECF + fb + (s) * 4])

  {
    const float smr = -(1.0f / 512.0f) * LOG2E;
    const float smh = -(1.0f / 512.0f) * TWOLOG2E;
#pragma unroll
    for (int j = 0; j < 4; ++j) {
      *(fv4*)&S[0 * SECF + fb + j * 4] = *(const fv4*)(Nhr + (size_t)(h0 + j) * 4);
      *(fv4*)&S[1 * SECF + fb + j * 4] = *(const fv4*)(Nhz + (size_t)(h0 + j) * 4);
      *(fv4*)&S[2 * SECF + fb + j * 4] = *(const fv4*)(Nhh + (size_t)(h0 + j) * 4);
      *(fv4*)&S[3 * SECF + fb + j * 4] = *(const fv4*)(Mhr + (size_t)(h0 + j) * 4) * smr;
      *(fv4*)&S[4 * SECF + fb + j * 4] = *(const fv4*)(Mhz + (size_t)(h0 + j) * 4) * smr;
      *(fv4*)&S[5 * SECF + fb + j * 4] = *(const fv4*)(Mhh + (size_t)(h0 + j) * 4) * smh;
    }
  }
  __syncthreads();   // once, outside the loop: order init vs exchange use

  float x[4];
  {
    fv4 a = *(const fv4*)(x0 + (size_t)b * Hv + h0);
#pragma unroll
    for (int j = 0; j < 4; ++j) x[j] = a[j];
  }
  const unsigned* trajU = traj + (size_t)b * Tv * Hv;
  const unsigned short* ihU = ihb + (size_t)b * Tv * Hv;
  const float* noiseU = noise + (size_t)b * Hv;

  Buf A, Bb;
  // asm-volatile loads: pinned at this program point, cannot be sunk.
  auto LOAD = [&](Buf& bf, int t) {
    const unsigned* p1 = trajU + (size_t)t * Hv + h0;
    asm volatile("global_load_dwordx4 %0, %1, off" : "=v"(bf.irz) : "v"(p1));
    const unsigned short* p2 = ihU + (size_t)t * Hv + h0;
    asm volatile("global_load_dwordx2 %0, %1, off" : "=v"(bf.ih2) : "v"(p2));
    const float* p3 = noiseU + (size_t)t * (Bv * Hv) + h0;
    asm volatile("global_load_dwordx4 %0, %1, off" : "=v"(bf.nz) : "v"(p3));
  };
  auto IHF = [](const Buf& bf, int j) -> float {
    unsigned v = bf.ih2[j >> 1];
    return bf2f((unsigned short)((j & 1) ? (v >> 16) : (v & 0xffffu)));
  };

  auto STEP = [&](const Buf& bf, int t, bool first) {
    // P1: partial rank-4 dots over this wave's 256 h
    float sr[4] = {0, 0, 0, 0}, sz[4] = {0, 0, 0, 0};
#pragma unroll
    for (int j = 0; j < 4; ++j) {
      fv4 nrj = LDQ(0, j), nzj = LDQ(1, j);
#pragma unroll
      for (int r = 0; r < 4; ++r) {
        sr[r] = fmaf(x[j], nrj[r], sr[r]);
        sz[r] = fmaf(x[j], nzj[r], sz[r]);
      }
    }
    // P2: in-wave trees + cross-wave exchange #1 (raw barrier, no vm drain)
#pragma unroll
    for (int r = 0; r < 4; ++r) { sr[r] = wave_red(sr[r]); sz[r] = wave_red(sz[r]); }
    if (lane == 0) {
      fv4 a = {sr[0], sr[1], sr[2], sr[3]}, c = {sz[0], sz[1], sz[2], sz[3]};
      *(fv4*)&S[XB1 + w * 8] = a;
      *(fv4*)&S[XB1 + w * 8 + 4] = c;
    }
    asm volatile("s_waitcnt lgkmcnt(0)" ::: "memory");
    __builtin_amdgcn_s_barrier();
    __builtin_amdgcn_sched_barrier(0);
    {
      const float* o = &S[XB1 + (w ^ 1) * 8];
#pragma unroll
      for (int r = 0; r < 4; ++r) { sr[r] += o[r]; sz[r] += o[4 + r]; }
    }
    // wait for this step's streamed inputs (issued >1 step ago)
    if (first) { asm volatile("s_waitcnt vmcnt(3)" ::: "memory"); }
    else       { asm volatile("s_waitcnt vmcnt(4)" ::: "memory"); }
    __builtin_amdgcn_sched_barrier(0);
    // P3: gate dots + sigmoids (shared rcp per r/z pair)
    float rxv[4], w02[4];
#pragma unroll
    for (int j = 0; j < 4; ++j) {
      fv4 mrj = LDQ(3, j), mzj = LDQ(4, j);
      float hr = fmaf(sr[3], mrj[3], fmaf(sr[2], mrj[2], fmaf(sr[1], mrj[1], sr[0] * mrj[0])));
      float hz = fmaf(sz[3], mzj[3], fmaf(sz[2], mzj[2], fmaf(sz[1], mzj[1], sz[0] * mzj[0])));
      unsigned wv = bf.irz[j];
      float tr = hr + __builtin_bit_cast(float, wv << 16);
      float tz = hz + __builtin_bit_cast(float, wv & 0xffff0000u);
      float er = __builtin_amdgcn_exp2f(tr);       // = e^{-arg_r}
      float ez = __builtin_amdgcn_exp2f(tz);
      float Ar = 1.0f + er, Az = 1.0f + ez;
      float R = __builtin_amdgcn_rcpf(Ar * Az);
      rxv[j] = (R * Az) * x[j];                    // sigmoid_r * x
      w02[j] = fmaf(R * Ar, -0.2f, 0.2f);          // 0.2*(1-sigmoid_z)
    }
    // P4: partial N_h dots
    float sh[4] = {0, 0, 0, 0};
#pragma unroll
    for (int j = 0; j < 4; ++j) {
      fv4 nhj = LDQ(2, j);
#pragma unroll
      for (int r = 0; r < 4; ++r) sh[r] = fmaf(rxv[j], nhj[r], sh[r]);
    }
    // P5: trees + exchange #2 (raw barrier)
#pragma unroll
    for (int r = 0; r < 4; ++r) sh[r] = wave_red(sh[r]);
    if (lane == 0) {
      fv4 a = {sh[0], sh[1], sh[2], sh[3]};
      *(fv4*)&S[XB2 + w * 4] = a;
    }
    asm volatile("s_waitcnt lgkmcnt(0)" ::: "memory");
    __builtin_amdgcn_s_barrier();
    __builtin_amdgcn_sched_barrier(0);
    {
      const float* o = &S[XB2 + (w ^ 1) * 4];
#pragma unroll
      for (int r = 0; r < 4; ++r) sh[r] += o[r];
    }
    // P6: hh dots, tanh with shared rcp per pair, state update
#pragma unroll
    for (int p = 0; p < 2; ++p) {
      const int j0 = 2 * p, j1 = 2 * p + 1;
      fv4 m0 = LDQ(5, j0), m1 = LDQ(5, j1);
      float hh0 = fmaf(sh[3], m0[3], fmaf(sh[2], m0[2], fmaf(sh[1], m0[1], sh[0] * m0[0])));
      float hh1 = fmaf(sh[3], m1[3], fmaf(sh[2], m1[2], fmaf(sh[1], m1[1], sh[0] * m1[0])));
      float t0 = fminf(hh0 + IHF(bf, j0), 44.0f);       // = -2L*a, clamped
      float t1 = fminf(hh1 + IHF(bf, j1), 44.0f);
      float e0 = __builtin_amdgcn_exp2f(t0);
      float e1 = __builtin_amdgcn_exp2f(t1);
      float A0 = 1.0f + e0, A1 = 1.0f + e1;
      float R = __builtin_amdgcn_rcpf(A0 * A1);
      float g0 = (1.0f - e0) * A1 * R;                  // tanh
      float g1 = (1.0f - e1) * A0 * R;
      float d0 = g0 - x[j0], d1 = g1 - x[j1];
      x[j0] = fmaf(0.05f, bf.nz[j0], x[j0]);
      x[j0] = fmaf(w02[j0], d0, x[j0]);
      x[j1] = fmaf(0.05f, bf.nz[j1], x[j1]);
      x[j1] = fmaf(w02[j1], d1, x[j1]);
    }
    float* po = (float*)(trajU + (size_t)t * Hv);
    fv4 s0 = {x[0], x[1], x[2], x[3]};
    *(fv4*)(po + h0) = s0;
  };

  LOAD(A, 0);
  {
    // first iteration peeled for the vmcnt(3) first-wait
    LOAD(Bb, 1);
    STEP(A, 0, true);
    LOAD(A, 2);
    STEP(Bb, 1, false);
  }
  for (int t = 2; t < Tv; t += 2) {
    LOAD(Bb, t + 1);
    STEP(A, t, false);
    int tn = (t + 2 > Tv - 1) ? (Tv - 1) : (t + 2);  // clamp: keeps queue invariant
    LOAD(A, tn);
    STEP(Bb, t + 1, false);
  }
  {
    fv4 s0 = {x[0], x[1], x[2], x[3]};
    *(fv4*)(xlast + (size_t)b * Hv + h0) = s0;
  }
#undef LDQ
}

// ---------------------------------------------------------------------------
// K3: output projection out[bt,o] = traj[bt,:] . W_out[o,:] + b_out[o]
// ---------------------------------------------------------------------------
__global__ __launch_bounds__(256) void outproj_kernel(
    const float* __restrict__ traj, const float* __restrict__ Wout,
    const float* __restrict__ bout, float* __restrict__ out)
{
  __shared__ __align__(16) unsigned short As[64][40];
  const int bt0 = blockIdx.x * 64;
  const int tid = threadIdx.x;
  const int wave = tid >> 6, lane = tid & 63;
  const int n = lane & 15, q = lane >> 4;
  const int o = wave * 16 + n;
  const float bo = bout[o];
  fv4 acc[4] = {{0.f,0.f,0.f,0.f},{0.f,0.f,0.f,0.f},{0.f,0.f,0.f,0.f},{0.f,0.f,0.f,0.f}};
  const int r = tid >> 2, ksg = (tid & 3) * 8;
  for (int ks = 0; ks < 16; ++ks) {
    __syncthreads();
    {
      const float* src = traj + (size_t)(bt0 + r) * Hv + ks * 32 + ksg;
      float4 v0 = *(const float4*)src, v1 = *(const float4*)(src + 4);
      unsigned short tmp[8];
      tmp[0] = f2bf(v0.x); tmp[1] = f2bf(v0.y); tmp[2] = f2bf(v0.z); tmp[3] = f2bf(v0.w);
      tmp[4] = f2bf(v1.x); tmp[5] = f2bf(v1.y); tmp[6] = f2bf(v1.z); tmp[7] = f2bf(v1.w);
      *(uv4*)&As[r][ksg] = *(uv4*)&tmp[0];
    }
    __syncthreads();
    const float* wp = Wout + (size_t)o * Hv + ks * 32 + q * 8;
    float4 w0 = *(const float4*)wp, w1 = *(const float4*)(wp + 4);
    bv8 bf;
    bf[0] = (short)f2bf(w0.x); bf[1] = (short)f2bf(w0.y);
    bf[2] = (short)f2bf(w0.z); bf[3] = (short)f2bf(w0.w);
    bf[4] = (short)f2bf(w1.x); bf[5] = (short)f2bf(w1.y);
    bf[6] = (short)f2bf(w1.z); bf[7] = (short)f2bf(w1.w);
#pragma unroll
    for (int sub = 0; sub < 4; ++sub) {
      bv8 af = *(const bv8*)&As[sub * 16 + n][q * 8];
      acc[sub] = __builtin_amdgcn_mfma_f32_16x16x32_bf16(af, bf, acc[sub], 0, 0, 0);
    }
  }
#pragma unroll
  for (int sub = 0; sub < 4; ++sub)
#pragma unroll
    for (int j = 0; j < 4; ++j) {
      const int row = bt0 + sub * 16 + q * 4 + j;
      out[(size_t)row * Ov + o] = acc[sub][j] + bo;
    }
}

// ---------------------------------------------------------------------------
extern "C" void kernel_launch(void* const* d_in, const int* in_sizes, int n_in,
                              void* d_out, int out_size, void* d_ws, size_t ws_size,
                              hipStream_t stream) {
  const float* u    = (const float*)d_in[0];
  const float* x0   = (const float*)d_in[1];
  const float* noise= (const float*)d_in[2];
  const float* Wir  = (const float*)d_in[3];
  const float* bir  = (const float*)d_in[4];
  const float* Wiz  = (const float*)d_in[5];
  const float* biz  = (const float*)d_in[6];
  const float* Wih  = (const float*)d_in[7];
  const float* bih  = (const float*)d_in[8];
  const float* Nhr  = (const float*)d_in[9];
  const float* Mhr  = (const float*)d_in[10];
  const float* Nhz  = (const float*)d_in[11];
  const float* Mhz  = (const float*)d_in[12];
  const float* Nhh  = (const float*)d_in[13];
  const float* Mhh  = (const float*)d_in[14];
  const float* Wout = (const float*)d_in[15];
  const float* bout = (const float*)d_in[16];

  float* out   = (float*)d_out;                    // [B,T,O]
  float* xlast = out + (size_t)Bv * Tv * Ov;       // [B,H]
  float* traj  = xlast + (size_t)Bv * Hv;          // [B,T,H]
  unsigned short* ihbuf = (unsigned short*)d_ws;   // [B*T*H] bf16 (64 MiB)

  proj_kernel<<<dim3(1024, 8, 1), 256, 0, stream>>>(
      u, Wir, bir, Wiz, biz, Wih, bih, (unsigned*)traj, ihbuf);
  scan_kernel<<<dim3(128, 1, 1), 128, 0, stream>>>(
      x0, noise, Nhr, Mhr, Nhz, Mhz, Nhh, Mhh, (unsigned*)traj, ihbuf, xlast);
  outproj_kernel<<<dim3(1024, 1, 1), 256, 0, stream>>>(traj, Wout, bout, out);
}